// Round 1
// baseline (342.378 us; speedup 1.0000x reference)
//
#include <hip/hip_runtime.h>

#define NQ 10
#define NL 4
// DIM = 1024 = 64 lanes x 16 regs. Index bit b (b=9-q): b>=4 -> lane bit (b-4), b<4 -> reg bit b.

__device__ __forceinline__ void cmul(float ar, float ai, float br, float bi,
                                     float& cr, float& ci) {
    cr = ar * br - ai * bi;
    ci = ar * bi + ai * br;
}

// Fuse Rx(t0)*Ry(t1)*Rz(t2) (row-vector composition order, matching the
// reference's einsum 'bmi,ij->bmj' = v @ G) into one 2x2 complex matrix.
__global__ void tq_prep_kernel(const float* __restrict__ theta, float* __restrict__ cs) {
    int i = blockIdx.x * blockDim.x + threadIdx.x;
    if (i >= NL * NQ) return;
    float hx = 0.5f * theta[i * 3 + 0];
    float hy = 0.5f * theta[i * 3 + 1];
    float hz = 0.5f * theta[i * 3 + 2];
    float cx = cosf(hx), sx = sinf(hx);
    float cy = cosf(hy), sy = sinf(hy);
    float cz = cosf(hz), sz = sinf(hz);
    // M = Rx * Ry
    float m00r =  cx * cy, m00i = -sx * sy;
    float m01r = -cx * sy, m01i = -sx * cy;
    float m10r =  cx * sy, m10i = -sx * cy;
    float m11r =  cx * cy, m11i =  sx * sy;
    // G = M * Rz,  Rz = diag(cz - i sz, cz + i sz)
    float g00r, g00i, g01r, g01i, g10r, g10i, g11r, g11i;
    cmul(m00r, m00i, cz, -sz, g00r, g00i);
    cmul(m10r, m10i, cz, -sz, g10r, g10i);
    cmul(m01r, m01i, cz,  sz, g01r, g01i);
    cmul(m11r, m11i, cz,  sz, g11r, g11i);
    float* o = cs + i * 8;
    o[0] = g00r; o[1] = g00i; o[2] = g01r; o[3] = g01i;
    o[4] = g10r; o[5] = g10i; o[6] = g11r; o[7] = g11i;
}

__global__ __launch_bounds__(256) void tq_main_kernel(
    const float* __restrict__ x, const float* __restrict__ encW,
    const float* __restrict__ encb, const float* __restrict__ cs,
    float* __restrict__ out, int batch) {
    int gtid = blockIdx.x * blockDim.x + threadIdx.x;
    int wave = gtid >> 6;
    int lane = threadIdx.x & 63;
    if (wave >= batch) return;

    float x0 = x[wave * 3 + 0], x1 = x[wave * 3 + 1], x2 = x[wave * 3 + 2];

    // Encoding angles: lane q (<10) computes cos/sin of its half-angle.
    float hc = 1.f, hs = 0.f;
    if (lane < NQ) {
        float t = 3.14159265358979323846f *
                  tanhf(x0 * encW[lane * 3 + 0] + x1 * encW[lane * 3 + 1] +
                        x2 * encW[lane * 3 + 2] + encb[lane]);
        float h = 0.5f * t;
        hc = cosf(h);
        hs = sinf(h);
    }
    float fc[NQ], fs[NQ];
#pragma unroll
    for (int q = 0; q < NQ; q++) {
        fc[q] = __shfl(hc, q, 64);
        fs[q] = __shfl(hs, q, 64);
    }

    // Post-encoding product state: amp(i) = prod_q (bit_q(i)==0 ? c_q : -s_q)
    float are[16], aim[16];
    float plane = 1.f;
#pragma unroll
    for (int q = 0; q < 6; q++) plane *= ((lane >> (5 - q)) & 1) ? -fs[q] : fc[q];
#pragma unroll
    for (int r = 0; r < 16; r++) {
        float v = plane;
        v *= ((r >> 3) & 1) ? -fs[6] : fc[6];
        v *= ((r >> 2) & 1) ? -fs[7] : fc[7];
        v *= ((r >> 1) & 1) ? -fs[8] : fc[8];
        v *= ((r     ) & 1) ? -fs[9] : fc[9];
        are[r] = v;
        aim[r] = 0.f;
    }

#pragma unroll 1
    for (int l = 0; l < NL; l++) {
        const float* csl = cs + l * NQ * 8;
#pragma unroll
        for (int q = 0; q < NQ; q++) {
            const float* g = csl + q * 8;
            float g00r = g[0], g00i = g[1], g01r = g[2], g01i = g[3];
            float g10r = g[4], g10i = g[5], g11r = g[6], g11i = g[7];
            if (q <= 5) {
                // pairing across lane bit k
                const int k = 5 - q;
                int bit = (lane >> k) & 1;
                float Pr = bit ? g11r : g00r, Pi = bit ? g11i : g00i;
                float Qr = bit ? g01r : g10r, Qi = bit ? g01i : g10i;
#pragma unroll
                for (int r = 0; r < 16; r++) {
                    float br = __shfl_xor(are[r], 1 << k, 64);
                    float bi = __shfl_xor(aim[r], 1 << k, 64);
                    float nr = Pr * are[r] - Pi * aim[r] + Qr * br - Qi * bi;
                    float ni = Pr * aim[r] + Pi * are[r] + Qr * bi + Qi * br;
                    are[r] = nr;
                    aim[r] = ni;
                }
            } else {
                // pairing across reg bit b
                const int b = 9 - q;
                const int m = 1 << b;
#pragma unroll
                for (int r0 = 0; r0 < 16; r0++) {
                    if (r0 & m) continue;
                    int r1 = r0 | m;
                    float a0r = are[r0], a0i = aim[r0];
                    float a1r = are[r1], a1i = aim[r1];
                    are[r0] = g00r * a0r - g00i * a0i + g10r * a1r - g10i * a1i;
                    aim[r0] = g00r * a0i + g00i * a0r + g10r * a1i + g10i * a1r;
                    are[r1] = g01r * a0r - g01i * a0i + g11r * a1r - g11i * a1i;
                    aim[r1] = g01r * a0i + g01i * a0r + g11r * a1i + g11i * a1r;
                }
            }
        }
        // CNOT ring (q, q+1 mod 10): control bit 9-q, target bit 9-((q+1)%10)
#pragma unroll
        for (int q = 0; q < NQ; q++) {
            if (q <= 4) {
                // control lane bit 5-q, target lane bit 4-q: cond. lane swap
                const int kc = 5 - q, kt = 4 - q;
                bool ctrl = (lane >> kc) & 1;
#pragma unroll
                for (int r = 0; r < 16; r++) {
                    float br = __shfl_xor(are[r], 1 << kt, 64);
                    float bi = __shfl_xor(aim[r], 1 << kt, 64);
                    are[r] = ctrl ? br : are[r];
                    aim[r] = ctrl ? bi : aim[r];
                }
            } else if (q == 5) {
                // control lane bit 0, target reg bit 3: cond. register swap
                bool ctrl = lane & 1;
#pragma unroll
                for (int r0 = 0; r0 < 8; r0++) {
                    int r1 = r0 + 8;
                    float t0 = are[r0], t1 = are[r1];
                    are[r0] = ctrl ? t1 : t0;
                    are[r1] = ctrl ? t0 : t1;
                    float u0 = aim[r0], u1 = aim[r1];
                    aim[r0] = ctrl ? u1 : u0;
                    aim[r1] = ctrl ? u0 : u1;
                }
            } else if (q <= 8) {
                // both bits in-register: compile-time register rename (free)
                const int cb = 9 - q, tb = 8 - q;
#pragma unroll
                for (int r = 0; r < 16; r++) {
                    if (((r >> cb) & 1) && !((r >> tb) & 1)) {
                        int r2 = r | (1 << tb);
                        float t = are[r]; are[r] = are[r2]; are[r2] = t;
                        float u = aim[r]; aim[r] = aim[r2]; aim[r2] = u;
                    }
                }
            } else {
                // q=9: control reg bit 0, target lane bit 5: uncond. pair swap
#pragma unroll
                for (int r = 1; r < 16; r += 2) {
                    are[r] = __shfl_xor(are[r], 32, 64);
                    aim[r] = __shfl_xor(aim[r], 32, 64);
                }
            }
        }
    }

    // Z expectations: out[q] = sum_i (1-2*bit_q(i)) * |amp_i|^2
    float tot = 0.f, z6 = 0.f, z7 = 0.f, z8 = 0.f, z9 = 0.f;
#pragma unroll
    for (int r = 0; r < 16; r++) {
        float p = are[r] * are[r] + aim[r] * aim[r];
        tot += p;
        z6 += ((r >> 3) & 1) ? -p : p;
        z7 += ((r >> 2) & 1) ? -p : p;
        z8 += ((r >> 1) & 1) ? -p : p;
        z9 += ((r     ) & 1) ? -p : p;
    }
    float z[NQ];
#pragma unroll
    for (int q = 0; q < 6; q++) z[q] = ((lane >> (5 - q)) & 1) ? -tot : tot;
    z[6] = z6; z[7] = z7; z[8] = z8; z[9] = z9;
#pragma unroll
    for (int q = 0; q < NQ; q++) {
#pragma unroll
        for (int off = 1; off < 64; off <<= 1) z[q] += __shfl_xor(z[q], off, 64);
    }
    if (lane == 0) {
#pragma unroll
        for (int q = 0; q < NQ; q++) out[wave * NQ + q] = z[q];
    }
}

extern "C" void kernel_launch(void* const* d_in, const int* in_sizes, int n_in,
                              void* d_out, int out_size, void* d_ws, size_t ws_size,
                              hipStream_t stream) {
    const float* x    = (const float*)d_in[0];
    const float* encW = (const float*)d_in[1];
    const float* encb = (const float*)d_in[2];
    const float* th   = (const float*)d_in[3];
    float* out = (float*)d_out;
    float* cs  = (float*)d_ws;  // 40 fused 2x2 complex gates = 320 floats
    int batch = in_sizes[0] / 3;

    tq_prep_kernel<<<1, 64, 0, stream>>>(th, cs);
    int total_threads = batch * 64;
    tq_main_kernel<<<(total_threads + 255) / 256, 256, 0, stream>>>(
        x, encW, encb, cs, out, batch);
}

// Round 2
// 302.361 us; speedup vs baseline: 1.1324x; 1.1324x over previous
//
#include <hip/hip_runtime.h>

#define NQ 10
#define NL 4
// DIM = 1024 = 64 lanes x 16 regs. Index bit b (b=9-q): b>=4 -> lane bit (b-4), b<4 -> reg bit b.

__device__ __forceinline__ void cmul(float ar, float ai, float br, float bi,
                                     float& cr, float& ci) {
    cr = ar * br - ai * bi;
    ci = ar * bi + ai * br;
}

// Fuse Rx(t0)*Ry(t1)*Rz(t2) (row-vector composition order, matching the
// reference's einsum 'bmi,ij->bmj' = v @ G) into one 2x2 complex matrix.
__global__ void tq_prep_kernel(const float* __restrict__ theta, float* __restrict__ cs) {
    int i = blockIdx.x * blockDim.x + threadIdx.x;
    if (i >= NL * NQ) return;
    float hx = 0.5f * theta[i * 3 + 0];
    float hy = 0.5f * theta[i * 3 + 1];
    float hz = 0.5f * theta[i * 3 + 2];
    float cx = cosf(hx), sx = sinf(hx);
    float cy = cosf(hy), sy = sinf(hy);
    float cz = cosf(hz), sz = sinf(hz);
    float m00r =  cx * cy, m00i = -sx * sy;
    float m01r = -cx * sy, m01i = -sx * cy;
    float m10r =  cx * sy, m10i = -sx * cy;
    float m11r =  cx * cy, m11i =  sx * sy;
    float g00r, g00i, g01r, g01i, g10r, g10i, g11r, g11i;
    cmul(m00r, m00i, cz, -sz, g00r, g00i);
    cmul(m10r, m10i, cz, -sz, g10r, g10i);
    cmul(m01r, m01i, cz,  sz, g01r, g01i);
    cmul(m11r, m11i, cz,  sz, g11r, g11i);
    float* o = cs + i * 8;
    o[0] = g00r; o[1] = g00i; o[2] = g01r; o[3] = g01i;
    o[4] = g10r; o[5] = g10i; o[6] = g11r; o[7] = g11i;
}

// xor-shuffle via ds_swizzle BitMode: offset = (xor<<10) | (0<<5) | 0x1F.
// Valid for xor masks <= 0x1F (stays within 32-lane groups).
template <int MASK>
__device__ __forceinline__ float swz(float v) {
    return __int_as_float(
        __builtin_amdgcn_ds_swizzle(__float_as_int(v), (MASK << 10) | 0x1F));
}

__device__ __forceinline__ float bperm(int addr, float v) {
    return __int_as_float(__builtin_amdgcn_ds_bpermute(addr, __float_as_int(v)));
}

// xor-shuffle for lane bit K; addr32 = (lane^32)<<2 precomputed.
template <int K>
__device__ __forceinline__ float xshf(float v, int addr32) {
    if constexpr (K == 5) {
        return bperm(addr32, v);
    } else {
        return swz<(1 << K)>(v);
    }
}

// Single-qubit gate on lane bit K. g = {g00r,g00i,g01r,g01i,g10r,g10i,g11r,g11i}
template <int K>
__device__ __forceinline__ void lane_gate(float (&are)[16], float (&aim)[16],
                                          const float* __restrict__ g, int lane,
                                          int addr32) {
    int bit = (lane >> K) & 1;
    float Pr = bit ? g[6] : g[0], Pi = bit ? g[7] : g[1];  // own-amp coeff
    float Qr = bit ? g[2] : g[4], Qi = bit ? g[3] : g[5];  // partner coeff
#pragma unroll
    for (int r = 0; r < 16; r++) {
        float br = xshf<K>(are[r], addr32);
        float bi = xshf<K>(aim[r], addr32);
        float nr = Pr * are[r] - Pi * aim[r] + Qr * br - Qi * bi;
        float ni = Pr * aim[r] + Pi * are[r] + Qr * bi + Qi * br;
        are[r] = nr;
        aim[r] = ni;
    }
}

// Single-qubit gate on register bit B (no lane traffic).
template <int B>
__device__ __forceinline__ void reg_gate(float (&are)[16], float (&aim)[16],
                                         const float* __restrict__ g) {
    float g00r = g[0], g00i = g[1], g01r = g[2], g01i = g[3];
    float g10r = g[4], g10i = g[5], g11r = g[6], g11i = g[7];
    const int m = 1 << B;
#pragma unroll
    for (int r0 = 0; r0 < 16; r0++) {
        if (r0 & m) continue;
        int r1 = r0 | m;
        float a0r = are[r0], a0i = aim[r0];
        float a1r = are[r1], a1i = aim[r1];
        are[r0] = g00r * a0r - g00i * a0i + g10r * a1r - g10i * a1i;
        aim[r0] = g00r * a0i + g00i * a0r + g10r * a1i + g10i * a1r;
        are[r1] = g01r * a0r - g01i * a0i + g11r * a1r - g11i * a1i;
        aim[r1] = g01r * a0i + g01i * a0r + g11r * a1i + g11i * a1r;
    }
}

__device__ __forceinline__ float redsum(float v, int addr32) {
    v += swz<1>(v);
    v += swz<2>(v);
    v += swz<4>(v);
    v += swz<8>(v);
    v += swz<16>(v);
    v += bperm(addr32, v);
    return v;
}

__global__ __launch_bounds__(256) void tq_main_kernel(
    const float* __restrict__ x, const float* __restrict__ encW,
    const float* __restrict__ encb, const float* __restrict__ cs,
    float* __restrict__ out, int batch) {
    int gtid = blockIdx.x * blockDim.x + threadIdx.x;
    int wave = gtid >> 6;
    int lane = threadIdx.x & 63;
    if (wave >= batch) return;

    const int addr32 = (lane ^ 32) << 2;
    // Composed gather permutation for CNOTs q=0..4 (applied q=0 first):
    // G(l) = g0(g1(g2(g3(g4(l))))), g_q(l) = l ^ (bit_{5-q}(l) << (4-q)).
    int s = lane;
    s ^= ((s >> 1) & 1);        // g4
    s ^= ((s >> 2) & 1) << 1;   // g3
    s ^= ((s >> 3) & 1) << 2;   // g2
    s ^= ((s >> 4) & 1) << 3;   // g1
    s ^= ((s >> 5) & 1) << 4;   // g0
    const int lanep = s << 2;

    float x0 = x[wave * 3 + 0], x1 = x[wave * 3 + 1], x2 = x[wave * 3 + 2];

    // Encoding angles: lane q (<10) computes cos/sin of its half-angle.
    float hc = 1.f, hs = 0.f;
    if (lane < NQ) {
        float t = 3.14159265358979323846f *
                  tanhf(x0 * encW[lane * 3 + 0] + x1 * encW[lane * 3 + 1] +
                        x2 * encW[lane * 3 + 2] + encb[lane]);
        float h = 0.5f * t;
        hc = cosf(h);
        hs = sinf(h);
    }
    float fc[NQ], fs[NQ];
#pragma unroll
    for (int q = 0; q < NQ; q++) {
        fc[q] = __shfl(hc, q, 64);
        fs[q] = __shfl(hs, q, 64);
    }

    // Post-encoding product state: amp(i) = prod_q (bit_q(i)==0 ? c_q : -s_q)
    float are[16], aim[16];
    float plane = 1.f;
#pragma unroll
    for (int q = 0; q < 6; q++) plane *= ((lane >> (5 - q)) & 1) ? -fs[q] : fc[q];
#pragma unroll
    for (int r = 0; r < 16; r++) {
        float v = plane;
        v *= ((r >> 3) & 1) ? -fs[6] : fc[6];
        v *= ((r >> 2) & 1) ? -fs[7] : fc[7];
        v *= ((r >> 1) & 1) ? -fs[8] : fc[8];
        v *= ((r     ) & 1) ? -fs[9] : fc[9];
        are[r] = v;
        aim[r] = 0.f;
    }

#pragma unroll 1
    for (int l = 0; l < NL; l++) {
        const float* csl = cs + l * NQ * 8;
        lane_gate<5>(are, aim, csl + 0,  lane, addr32);  // q=0
        lane_gate<4>(are, aim, csl + 8,  lane, addr32);  // q=1
        lane_gate<3>(are, aim, csl + 16, lane, addr32);  // q=2
        lane_gate<2>(are, aim, csl + 24, lane, addr32);  // q=3
        lane_gate<1>(are, aim, csl + 32, lane, addr32);  // q=4
        lane_gate<0>(are, aim, csl + 40, lane, addr32);  // q=5
        reg_gate<3>(are, aim, csl + 48);                 // q=6
        reg_gate<2>(are, aim, csl + 56);                 // q=7
        reg_gate<1>(are, aim, csl + 64);                 // q=8
        reg_gate<0>(are, aim, csl + 72);                 // q=9

        // CNOT ring. q=0..4 fused into one lane permutation:
#pragma unroll
        for (int r = 0; r < 16; r++) {
            are[r] = bperm(lanep, are[r]);
            aim[r] = bperm(lanep, aim[r]);
        }
        // q=5: control lane bit 0, target reg bit 3 -> conditional reg swap
        {
            bool ctrl = lane & 1;
#pragma unroll
            for (int r0 = 0; r0 < 8; r0++) {
                int r1 = r0 + 8;
                float t0 = are[r0], t1 = are[r1];
                are[r0] = ctrl ? t1 : t0;
                are[r1] = ctrl ? t0 : t1;
                float u0 = aim[r0], u1 = aim[r1];
                aim[r0] = ctrl ? u1 : u0;
                aim[r1] = ctrl ? u0 : u1;
            }
        }
        // q=6..8: both bits in-register -> compile-time register renames (free)
#pragma unroll
        for (int q = 6; q <= 8; q++) {
            const int cb = 9 - q, tb = 8 - q;
#pragma unroll
            for (int r = 0; r < 16; r++) {
                if (((r >> cb) & 1) && !((r >> tb) & 1)) {
                    int r2 = r | (1 << tb);
                    float t = are[r]; are[r] = are[r2]; are[r2] = t;
                    float u = aim[r]; aim[r] = aim[r2]; aim[r2] = u;
                }
            }
        }
        // q=9: control reg bit 0 (odd regs), target lane bit 5 -> xor-32 swap
#pragma unroll
        for (int r = 1; r < 16; r += 2) {
            are[r] = bperm(addr32, are[r]);
            aim[r] = bperm(addr32, aim[r]);
        }
    }

    // Z expectations: out[q] = sum_i (1-2*bit_q(i)) * |amp_i|^2
    float tot = 0.f, z6 = 0.f, z7 = 0.f, z8 = 0.f, z9 = 0.f;
#pragma unroll
    for (int r = 0; r < 16; r++) {
        float p = are[r] * are[r] + aim[r] * aim[r];
        tot += p;
        z6 += ((r >> 3) & 1) ? -p : p;
        z7 += ((r >> 2) & 1) ? -p : p;
        z8 += ((r >> 1) & 1) ? -p : p;
        z9 += ((r     ) & 1) ? -p : p;
    }
    float z[NQ];
#pragma unroll
    for (int q = 0; q < 6; q++) z[q] = ((lane >> (5 - q)) & 1) ? -tot : tot;
    z[6] = z6; z[7] = z7; z[8] = z8; z[9] = z9;
#pragma unroll
    for (int q = 0; q < NQ; q++) z[q] = redsum(z[q], addr32);

    // Coalesced-ish store: lane q writes z[q].
    float o = z[0];
#pragma unroll
    for (int q = 1; q < NQ; q++) o = (lane == q) ? z[q] : o;
    if (lane < NQ) out[wave * NQ + lane] = o;
}

extern "C" void kernel_launch(void* const* d_in, const int* in_sizes, int n_in,
                              void* d_out, int out_size, void* d_ws, size_t ws_size,
                              hipStream_t stream) {
    const float* x    = (const float*)d_in[0];
    const float* encW = (const float*)d_in[1];
    const float* encb = (const float*)d_in[2];
    const float* th   = (const float*)d_in[3];
    float* out = (float*)d_out;
    float* cs  = (float*)d_ws;  // 40 fused 2x2 complex gates = 320 floats
    int batch = in_sizes[0] / 3;

    tq_prep_kernel<<<1, 64, 0, stream>>>(th, cs);
    int total_threads = batch * 64;
    tq_main_kernel<<<(total_threads + 255) / 256, 256, 0, stream>>>(
        x, encW, encb, cs, out, batch);
}

// Round 5
// 112.087 us; speedup vs baseline: 3.0546x; 2.6975x over previous
//
#include <hip/hip_runtime.h>
#include <stdint.h>

#define NQ 10
#define NL 4

typedef unsigned int u32;
typedef _Float16 f16x8 __attribute__((ext_vector_type(8)));
typedef float f32x16 __attribute__((ext_vector_type(16)));
typedef u32 u32x4 __attribute__((ext_vector_type(4)));

// ---------- CNOT-ring permutation (XOR-linear), derived in closed form ----------
// F(i) = g0(g1(...g9(i))): b9=a9^a0, b8=a8^a9^a0, b_k=a_k^a_{k+1} (k=0..7).
constexpr u32 FRc(u32 r) {  // F(r<<5), r = 5-bit row
    u32 r0 = r & 1, r1 = (r >> 1) & 1, r2 = (r >> 2) & 1, r3 = (r >> 3) & 1, r4 = (r >> 4) & 1;
    return (r4 << 9) | ((r3 ^ r4) << 8) | ((r2 ^ r3) << 7) | ((r1 ^ r2) << 6) |
           ((r0 ^ r1) << 5) | (r0 << 4);
}
constexpr u32 FCc(u32 c) {  // F(c), c = 5-bit col
    u32 c0 = c & 1, c1 = (c >> 1) & 1, c2 = (c >> 2) & 1, c3 = (c >> 3) & 1, c4 = (c >> 4) & 1;
    return (c0 << 9) | (c0 << 8) | (c4 << 4) | ((c3 ^ c4) << 3) | ((c2 ^ c3) << 2) |
           ((c1 ^ c2) << 1) | (c0 ^ c1);
}
// F^-1 (prefix-xor form), verified F(F^-1(x)) == x symbolically.
constexpr u32 FIr(u32 r) {  // F^-1(row<<5)
    u32 r0 = r & 1, r1 = (r >> 1) & 1, r2 = (r >> 2) & 1, r3 = (r >> 3) & 1, r4 = (r >> 4) & 1;
    u32 P = r0 ^ r1 ^ r2 ^ r3 ^ r4;
    return ((r0 ^ r1 ^ r2 ^ r3) << 9) | ((r3 ^ r4) << 8) | ((r2 ^ r3 ^ r4) << 7) |
           ((r1 ^ r2 ^ r3 ^ r4) << 6) | (P << 5) | (P << 4) | (P << 3) | (P << 2) | (P << 1) | P;
}
constexpr u32 FIcf(u32 c) {  // F^-1(col)
    u32 c0 = c & 1, c1 = (c >> 1) & 1, c2 = (c >> 2) & 1, c3 = (c >> 3) & 1, c4 = (c >> 4) & 1;
    u32 Q = c0 ^ c1 ^ c2 ^ c3 ^ c4;
    return (Q << 9) | (c4 << 4) | ((c3 ^ c4) << 3) | ((c2 ^ c3 ^ c4) << 2) |
           ((c1 ^ c2 ^ c3 ^ c4) << 1) | Q;
}

// ---------- small helpers ----------
__device__ __forceinline__ f32x16 mfma16(f16x8 a, f16x8 b, f32x16 c) {
    return __builtin_amdgcn_mfma_f32_32x32x16_f16(a, b, c, 0, 0, 0);
}
__device__ __forceinline__ f32x16 zero16() {
    f32x16 z;
#pragma unroll
    for (int i = 0; i < 16; i++) z[i] = 0.f;
    return z;
}
__device__ __forceinline__ f16x8 negf(f16x8 v) {
    u32x4 u = __builtin_bit_cast(u32x4, v);
#pragma unroll
    for (int i = 0; i < 4; i++) u[i] ^= 0x80008000u;
    return __builtin_bit_cast(f16x8, u);
}
__device__ __forceinline__ u32 pk2(float re, float im) {
    auto h = __builtin_amdgcn_cvt_pkrtz(re, im);  // __fp16 ext_vector(2)
    return __builtin_bit_cast(u32, h);
}
__device__ __forceinline__ u32 permlo(u32 a, u32 b) {  // lo16(a) | lo16(b)<<16
    return __builtin_amdgcn_perm(b, a, 0x05040100u);
}
__device__ __forceinline__ u32 permhi(u32 a, u32 b) {  // hi16(a) | hi16(b)<<16
    return __builtin_amdgcn_perm(b, a, 0x07060302u);
}
__device__ __forceinline__ f16x8 mk8(u32 a, u32 b, u32 c, u32 d) {
    u32x4 v;
    v[0] = a; v[1] = b; v[2] = c; v[3] = d;
    return __builtin_bit_cast(f16x8, v);
}
template <int MASK>
__device__ __forceinline__ float swz(float v) {
    return __int_as_float(
        __builtin_amdgcn_ds_swizzle(__float_as_int(v), (MASK << 10) | 0x1F));
}
__device__ __forceinline__ float bperm(int addr, float v) {
    return __int_as_float(__builtin_amdgcn_ds_bpermute(addr, __float_as_int(v)));
}
__device__ __forceinline__ void cmulh(float ar, float ai, float br, float bi,
                                      float& cr, float& ci) {
    cr = ar * br - ai * bi;
    ci = ar * bi + ai * br;
}

// ---------- prep: fused gates -> Kronecker factors W,V in MFMA fragment layout ----------
// frag layout (f16): fragIdx f = (((l*2+mat)*2+part)*2+kh); element = frag[(f*64+lane)*8+j]
//   mat 0 = W (A-operand of GEMM1): W[m][k] = prod_{q=0..4} G_q[bit_q(k)][bit_q(m)]
//   mat 1 = V (B-operand of GEMM2): V[k][n] = prod_{q=5..9} G_q[bit_q(k)][bit_q(n)]
//   m/n = lane&31, k = kh*16 + (lane>>5)*8 + j   (bit_q = bit (4-u) of the 5-bit index)
// NOTE: index space is 2048 threads (l=4 layers); launch <<<2,1024>>>.
__global__ void tq_prep(const float* __restrict__ theta, uint16_t* __restrict__ frag) {
    __shared__ float g[NL * NQ][8];
    int tt = threadIdx.x;
    if (tt < NL * NQ) {
        float hx = 0.5f * theta[tt * 3 + 0];
        float hy = 0.5f * theta[tt * 3 + 1];
        float hz = 0.5f * theta[tt * 3 + 2];
        float cx = cosf(hx), sx = sinf(hx);
        float cy = cosf(hy), sy = sinf(hy);
        float cz = cosf(hz), sz = sinf(hz);
        float m00r = cx * cy, m00i = -sx * sy;
        float m01r = -cx * sy, m01i = -sx * cy;
        float m10r = cx * sy, m10i = -sx * cy;
        float m11r = cx * cy, m11i = sx * sy;
        float g00r, g00i, g01r, g01i, g10r, g10i, g11r, g11i;
        cmulh(m00r, m00i, cz, -sz, g00r, g00i);
        cmulh(m10r, m10i, cz, -sz, g10r, g10i);
        cmulh(m01r, m01i, cz, sz, g01r, g01i);
        cmulh(m11r, m11i, cz, sz, g11r, g11i);
        g[tt][0] = g00r; g[tt][1] = g00i; g[tt][2] = g01r; g[tt][3] = g01i;
        g[tt][4] = g10r; g[tt][5] = g10i; g[tt][6] = g11r; g[tt][7] = g11i;
    }
    __syncthreads();
    int t = blockIdx.x * blockDim.x + tt;  // 0..2047
    int lane = t & 63, kh = (t >> 6) & 1, part = (t >> 7) & 1, mat = (t >> 8) & 1, l = t >> 9;
    int mn = lane & 31, hf = (lane >> 5) & 1;
#pragma unroll
    for (int j = 0; j < 8; j++) {
        int k = kh * 16 + hf * 8 + j;
        float pr = 1.f, pi = 0.f;
#pragma unroll
        for (int u = 0; u < 5; u++) {
            int q = mat ? (5 + u) : u;
            int bi_ = (k >> (4 - u)) & 1;
            int bo_ = (mn >> (4 - u)) & 1;
            const float* gg = g[l * NQ + q];
            float er = gg[(bi_ * 2 + bo_) * 2 + 0];
            float ei = gg[(bi_ * 2 + bo_) * 2 + 1];
            float nr, ni;
            cmulh(pr, pi, er, ei, nr, ni);
            pr = nr;
            pi = ni;
        }
        float v = part ? pi : pr;
        _Float16 h = (_Float16)v;
        frag[t * 8 + j] = __builtin_bit_cast(unsigned short, h);
    }
}

// ---------- main: one wave per sample; state = 32x32 complex in MFMA fragments ----------
__global__ __launch_bounds__(256) void tq_main(
    const float* __restrict__ x, const float* __restrict__ encW,
    const float* __restrict__ encb, const uint16_t* __restrict__ frag,
    float* __restrict__ out, int batch) {
    __shared__ u32 smem[4 * 1056];
    int tid = threadIdx.x;
    int wave = (blockIdx.x * blockDim.x + tid) >> 6;
    int lane = tid & 63;
    if (wave >= batch) return;
    u32* slab = smem + (tid >> 6) * 1056;
    const int col = lane & 31;
    const int half = lane >> 5;
    const int addr32 = (lane ^ 32) << 2;
    const u32 Fc5 = FCc((u32)col);
    const u32 FIc_l = FIcf((u32)col);

    // ---- encoding: product state after RY(enc) on |0..0>, amp factor per qubit: bit? -s : c
    float x0 = x[wave * 3 + 0], x1 = x[wave * 3 + 1], x2 = x[wave * 3 + 2];
    float hc = 1.f, hs = 0.f;
    if (lane < NQ) {
        float tta = 3.14159265358979323846f *
                    tanhf(x0 * encW[lane * 3 + 0] + x1 * encW[lane * 3 + 1] +
                          x2 * encW[lane * 3 + 2] + encb[lane]);
        float h = 0.5f * tta;
        hc = cosf(h);
        hs = sinf(h);
    }
    float fcv[NQ], fsv[NQ];
#pragma unroll
    for (int q = 0; q < NQ; q++) {
        fcv[q] = __shfl(hc, q, 64);
        fsv[q] = __shfl(hs, q, 64);
    }
    // col factor (qubits 5..9 <-> col bits 4..0)
    float colf = 1.f;
    colf *= ((col >> 4) & 1) ? -fsv[5] : fcv[5];
    colf *= ((col >> 3) & 1) ? -fsv[6] : fcv[6];
    colf *= ((col >> 2) & 1) ? -fsv[7] : fcv[7];
    colf *= ((col >> 1) & 1) ? -fsv[8] : fcv[8];
    colf *= (col & 1) ? -fsv[9] : fcv[9];
    // row factors: r = kh*16 + half*8 + j; qubit0<-bit4=kh, qubit1<-bit3=half, q2..4<-j
    float f1h = half ? -fsv[1] : fcv[1];
    float gj[8];
#pragma unroll
    for (int j = 0; j < 8; j++) {
        gj[j] = ((j & 4) ? -fsv[2] : fcv[2]) * ((j & 2) ? -fsv[3] : fcv[3]) *
                ((j & 1) ? -fsv[4] : fcv[4]);
    }
    f16x8 Sr0, Sr1, Si0, Si1;
#pragma unroll
    for (int j = 0; j < 8; j++) {
        Sr0[j] = (_Float16)(fcv[0] * f1h * gj[j] * colf);
        Sr1[j] = (_Float16)(-fsv[0] * f1h * gj[j] * colf);
        Si0[j] = (_Float16)0.f;
        Si1[j] = (_Float16)0.f;
    }

    const f16x8* fr = (const f16x8*)frag;
#define FRAG(l, mat, part, kh) fr[(((((l)*2 + (mat)) * 2 + (part)) * 2 + (kh)) * 64) + lane]

    f32x16 Ur, Ui;
#pragma unroll
    for (int l = 0; l < NL; l++) {
        f16x8 Wr0 = FRAG(l, 0, 0, 0), Wr1 = FRAG(l, 0, 0, 1);
        f16x8 Wi0 = FRAG(l, 0, 1, 0), Wi1 = FRAG(l, 0, 1, 1);
        f16x8 Vr0 = FRAG(l, 1, 0, 0), Vr1 = FRAG(l, 1, 0, 1);
        f16x8 Vi0 = FRAG(l, 1, 1, 0), Vi1 = FRAG(l, 1, 1, 1);

        // GEMM1: T = W * S (complex), T in C-layout fp32
        f32x16 Tr = zero16(), Ti = zero16();
        Tr = mfma16(Wr0, Sr0, Tr);
        Tr = mfma16(Wr1, Sr1, Tr);
        Ti = mfma16(Wi0, Sr0, Ti);
        Ti = mfma16(Wi1, Sr1, Ti);
        if (l > 0) {
            f16x8 nSi0 = negf(Si0), nSi1 = negf(Si1);
            Tr = mfma16(Wi0, nSi0, Tr);
            Tr = mfma16(Wi1, nSi1, Tr);
            Ti = mfma16(Wr0, Si0, Ti);
            Ti = mfma16(Wr1, Si1, Ti);
        }

        // RT1: C-layout -> A-layout via LDS, stride 33 (bank-conflict-free both ways)
        {
            u32* wb = slab + col + half * (4 * 33);
#pragma unroll
            for (int gi = 0; gi < 16; gi++) {
                int rb = (gi & 3) + 8 * (gi >> 2);
                wb[rb * 33] = pk2(Tr[gi], Ti[gi]);
            }
        }
        u32 ta[16];
        {
            u32* rb = slab + col * 33 + half * 8;
#pragma unroll
            for (int kh = 0; kh < 2; kh++)
#pragma unroll
                for (int j = 0; j < 8; j++) ta[kh * 8 + j] = rb[kh * 16 + j];
        }
        f16x8 TAr0 = mk8(permlo(ta[0], ta[1]), permlo(ta[2], ta[3]),
                         permlo(ta[4], ta[5]), permlo(ta[6], ta[7]));
        f16x8 TAr1 = mk8(permlo(ta[8], ta[9]), permlo(ta[10], ta[11]),
                         permlo(ta[12], ta[13]), permlo(ta[14], ta[15]));
        f16x8 TAi0 = mk8(permhi(ta[0], ta[1]), permhi(ta[2], ta[3]),
                         permhi(ta[4], ta[5]), permhi(ta[6], ta[7]));
        f16x8 TAi1 = mk8(permhi(ta[8], ta[9]), permhi(ta[10], ta[11]),
                         permhi(ta[12], ta[13]), permhi(ta[14], ta[15]));

        // GEMM2: U = T * V (complex), U in C-layout fp32
        Ur = zero16();
        Ui = zero16();
        Ur = mfma16(TAr0, Vr0, Ur);
        Ur = mfma16(TAr1, Vr1, Ur);
        {
            f16x8 nTAi0 = negf(TAi0), nTAi1 = negf(TAi1);
            Ur = mfma16(nTAi0, Vi0, Ur);
            Ur = mfma16(nTAi1, Vi1, Ur);
        }
        Ui = mfma16(TAr0, Vi0, Ui);
        Ui = mfma16(TAr1, Vi1, Ui);
        Ui = mfma16(TAi0, Vr0, Ui);
        Ui = mfma16(TAi1, Vr1, Ui);

        if (l < NL - 1) {
            // RT2: apply CNOT-ring permutation F and emit next-layer B-layout S frags.
            // write C-layout stride-32 (banks=col), gather-read at F(r*32+c).
            {
                u32* wb = slab + col + half * (4 * 32);
#pragma unroll
                for (int gi = 0; gi < 16; gi++) {
                    int rb = (gi & 3) + 8 * (gi >> 2);
                    wb[rb * 32] = pk2(Ur[gi], Ui[gi]);
                }
            }
            u32 sb[16];
            {
                u32 fh = Fc5 ^ (half ? FRc(8) : 0u);
#pragma unroll
                for (int kh = 0; kh < 2; kh++)
#pragma unroll
                    for (int j = 0; j < 8; j++)
                        sb[kh * 8 + j] = slab[FRc(kh * 16 + j) ^ fh];
            }
            Sr0 = mk8(permlo(sb[0], sb[1]), permlo(sb[2], sb[3]),
                      permlo(sb[4], sb[5]), permlo(sb[6], sb[7]));
            Sr1 = mk8(permlo(sb[8], sb[9]), permlo(sb[10], sb[11]),
                      permlo(sb[12], sb[13]), permlo(sb[14], sb[15]));
            Si0 = mk8(permhi(sb[0], sb[1]), permhi(sb[2], sb[3]),
                      permhi(sb[4], sb[5]), permhi(sb[6], sb[7]));
            Si1 = mk8(permhi(sb[8], sb[9]), permhi(sb[10], sb[11]),
                      permhi(sb[12], sb[13]), permhi(sb[14], sb[15]));
        }
    }

    // ---- epilogue: probs in fp32 from U (pre-permutation); fold final F into Z signs.
    // out_q = sum_j sign(bit_{9-q}(F^-1(j))) * |U(j)|^2
    float acc[NQ];
#pragma unroll
    for (int q = 0; q < NQ; q++) acc[q] = 0.f;
#pragma unroll
    for (int gi = 0; gi < 16; gi++) {
        int rb = (gi & 3) + 8 * (gi >> 2);
        u32 minv = FIr((u32)rb) ^ (half ? FIr(4) : 0u) ^ FIc_l;
        float p = Ur[gi] * Ur[gi] + Ui[gi] * Ui[gi];
        float np = -p;
#pragma unroll
        for (int q = 0; q < NQ; q++) acc[q] += ((minv >> (9 - q)) & 1) ? np : p;
    }
#pragma unroll
    for (int q = 0; q < NQ; q++) {
        float v = acc[q];
        v += swz<1>(v);
        v += swz<2>(v);
        v += swz<4>(v);
        v += swz<8>(v);
        v += swz<16>(v);
        v += bperm(addr32, v);
        acc[q] = v;
    }
    float o = acc[0];
#pragma unroll
    for (int q = 1; q < NQ; q++) o = (lane == q) ? acc[q] : o;
    if (lane < NQ) out[wave * NQ + lane] = o;
}

extern "C" void kernel_launch(void* const* d_in, const int* in_sizes, int n_in,
                              void* d_out, int out_size, void* d_ws, size_t ws_size,
                              hipStream_t stream) {
    const float* x = (const float*)d_in[0];
    const float* encW = (const float*)d_in[1];
    const float* encb = (const float*)d_in[2];
    const float* th = (const float*)d_in[3];
    float* out = (float*)d_out;
    uint16_t* frag = (uint16_t*)d_ws;  // 4 layers * 2 mats * 2 parts * 2 kh * 64 lanes * 8 = 16384 f16
    int batch = in_sizes[0] / 3;

    tq_prep<<<2, 1024, 0, stream>>>(th, frag);
    int total_threads = batch * 64;
    tq_main<<<(total_threads + 255) / 256, 256, 0, stream>>>(x, encW, encb, frag, out, batch);
}